// Round 17
// baseline (305.414 us; speedup 1.0000x reference)
//
#include <hip/hip_runtime.h>

// ---------------- constants ----------------
#define B_     16
#define WDIM   512
#define CIN_   512
#define COUT_  512
#define HH     64
#define KC     32           // channels per K-chunk
#define NCHUNK (CIN_/KC)    // 16
#define AFFINE_WG 0.044194173824159216f   // 1/sqrt(512)
#define GAIN_  1.4142135623730951f
#define CLAMP_ 256.0f

typedef __attribute__((ext_vector_type(4))) float f32x4;
typedef __attribute__((ext_vector_type(8))) short bf16x8;
typedef __attribute__((ext_vector_type(8))) unsigned short u16x8;

__device__ __forceinline__ unsigned short f2bf(float f) {
    union { float f; unsigned u; } un; un.f = f;
    unsigned u = un.u;
    u += 0x7FFFu + ((u >> 16) & 1u);   // round-to-nearest-even
    return (unsigned short)(u >> 16);
}

__device__ __forceinline__ void gl_lds16(const void* g, void* l) {
    __builtin_amdgcn_global_load_lds(
        reinterpret_cast<const __attribute__((address_space(1))) unsigned int*>(
            reinterpret_cast<uintptr_t>(g)),
        reinterpret_cast<__attribute__((address_space(3))) unsigned int*>(
            reinterpret_cast<uintptr_t>(l)),
        16, 0, 0);
}

// ------- fused prep A: affine (32) | wnorm (512) | wprep (128) -------
__global__ void k_prepA(const float* __restrict__ w, const float* __restrict__ aw,
                        const float* __restrict__ ab, const float* __restrict__ cw,
                        float* __restrict__ s, float* __restrict__ part,
                        float* __restrict__ alpha, float* __restrict__ Q,
                        unsigned short* __restrict__ wb) {
    const int bi  = blockIdx.x;
    const int tid = threadIdx.x;
    __shared__ float redA[256];
    __shared__ float qsh[512];
    __shared__ float a_sh;
    __shared__ char tile[36864];

    if (bi < 32) {
        const int b = bi >> 1;
        const int c = ((bi & 1) << 8) + tid;
        const f32x4* wr = (const f32x4*)(w + (size_t)b * WDIM);
        const f32x4* ar = (const f32x4*)(aw + (size_t)c * WDIM);
        float acc = 0.f;
        #pragma unroll 4
        for (int k = 0; k < WDIM / 4; ++k) {
            f32x4 a = ar[k], bb = wr[k];
            acc += a[0]*bb[0] + a[1]*bb[1] + a[2]*bb[2] + a[3]*bb[3];
        }
        float sv = acc * AFFINE_WG + ab[c];
        s[b * CIN_ + c] = sv;
        redA[tid] = sv * sv;
        __syncthreads();
        for (int off = 128; off > 0; off >>= 1) {
            if (tid < off) redA[tid] += redA[tid + off];
            __syncthreads();
        }
        if (tid == 0) part[bi] = redA[0];
    } else if (bi < 544) {
        const int o = bi - 32;
        float tot = 0.f;
        #pragma unroll
        for (int half = 0; half < 2; ++half) {
            const int c = tid + half * 256;
            const float* p = cw + ((size_t)o * 512 + c) * 9;
            float qs = 0.f;
            #pragma unroll
            for (int t = 0; t < 9; ++t) { float v = p[t]; qs += v * v; }
            qsh[c] = qs; tot += qs;
        }
        redA[tid] = tot; __syncthreads();
        for (int off = 128; off > 0; off >>= 1) {
            if (tid < off) redA[tid] += redA[tid + off];
            __syncthreads();
        }
        if (tid == 0) { a_sh = rsqrtf(redA[0] * (1.0f / 4608.0f)); alpha[o] = a_sh; }
        __syncthreads();
        const float a2 = a_sh * a_sh;
        Q[(size_t)o * 512 + tid]       = a2 * qsh[tid];
        Q[(size_t)o * 512 + tid + 256] = a2 * qsh[tid + 256];
    } else {
        const int p = bi - 544;                   // 0..127 = ot*16+cc
        const int ot = p >> 4, cc = p & 15;
        const float* base = cw + ((size_t)(ot * 64) * 512 + cc * 32) * 9;
        #pragma unroll
        for (int k = 0; k < 18; ++k) {
            const int lin4 = tid + k * 256;       // f32x4 granule, 4608 total
            const int row  = lin4 / 72;           // o within tile
            const int i4   = lin4 - row * 72;
            const f32x4 v = *(const f32x4*)(base + (size_t)row * 4608 + i4 * 4);
            #pragma unroll
            for (int j = 0; j < 4; ++j) {
                const int e   = i4 * 4 + j;       // within row: c*9+tap
                const int c   = e / 9;
                const int tap = e - c * 9;
                const int byte = ((tap * 2048 + row * 32 + c) << 1) ^ ((row & 6) << 3);
                *(unsigned short*)(tile + byte) = f2bf(v[j]);
            }
        }
        __syncthreads();
        u16x8* dst = (u16x8*)(wb + (size_t)p * 18432);
        const u16x8* src = (const u16x8*)tile;
        #pragma unroll
        for (int k = 0; k < 9; ++k) dst[tid + k * 256] = src[tid + k * 256];
    }
}

// ---------------- fused prep B: g (32) | xprep (2048) ----------------
__global__ void k_prepB(const float* __restrict__ x, const float* __restrict__ s,
                        const float* __restrict__ part, const float* __restrict__ Q,
                        const float* __restrict__ alpha, const float* __restrict__ ema,
                        float* __restrict__ g, unsigned short* __restrict__ xbf) {
    const int bi  = blockIdx.x;
    const int tid = threadIdx.x;
    __shared__ float rs2_sh;
    __shared__ char tile[8 * 4096];

    if (bi < 32) {
        const int b = bi >> 1;
        const int o = ((bi & 1) << 8) + tid;
        if (tid == 0) {
            float t = 0.f;
            #pragma unroll
            for (int i = 0; i < 32; ++i) t += part[i];
            rs2_sh = 8192.0f / t;          // rs^2
        }
        __syncthreads();
        const f32x4* sh = (const f32x4*)(s + (size_t)b * CIN_);
        const f32x4* qq = (const f32x4*)(Q + (size_t)o * CIN_);
        float d = 0.f;
        #pragma unroll 4
        for (int k = 0; k < CIN_ / 4; ++k) {
            f32x4 a = sh[k], q4 = qq[k];
            d += a[0]*a[0]*q4[0] + a[1]*a[1]*q4[1] + a[2]*a[2]*q4[2] + a[3]*a[3]*q4[3];
        }
        const float ig = rsqrtf(ema[0]);
        g[b * COUT_ + o] = alpha[o] * rsqrtf(d * rs2_sh + 1e-8f) * ig;
    } else {
        if (tid == 0) {
            float t = 0.f;
            #pragma unroll
            for (int i = 0; i < 32; ++i) t += part[i];
            rs2_sh = rsqrtf(t * (1.0f / 8192.0f));   // rs
        }
        __syncthreads();
        const float rs = rs2_sh;
        const int blk = bi - 32;                   // 0..2047
        const int b  = blk >> 7;
        const int cc = (blk >> 3) & 15;
        const int rg = blk & 7;
        const int c   = tid >> 3;                  // 0..31
        const int k8  = tid & 7;                   // 8-col segment
        const float sc = s[b * CIN_ + cc * 32 + c] * rs;
        const float* src = x + (((size_t)(b * CIN_ + cc * 32 + c)) * HH + rg * 8) * HH + k8 * 8;
        #pragma unroll
        for (int row = 0; row < 8; ++row) {
            const f32x4 v0 = *(const f32x4*)(src + (size_t)row * HH);
            const f32x4 v1 = *(const f32x4*)(src + (size_t)row * HH + 4);
            #pragma unroll
            for (int q = 0; q < 8; ++q) {
                const float v = (q < 4) ? v0[q] : v1[q - 4];
                const int col = k8 * 8 + q + 1;                 // lds col 1..64
                const int byte = ((col * 64 + 2 * c) ^ ((col & 6) << 3)) - 64;
                *(unsigned short*)(tile + row * 4096 + byte) = f2bf(v * sc);
            }
        }
        __syncthreads();
        unsigned short* dst = xbf + ((size_t)(b * 16 + cc) * 64 + rg * 8) * 2048;
        const u16x8* tsrc = (const u16x8*)tile;
        #pragma unroll
        for (int k = 0; k < 8; ++k)
            *(u16x8*)(dst + (size_t)(tid + k * 256) * 8) = tsrc[tid + k * 256];
    }
}

// ------- main conv: champion + 2-tap-deep register pipeline + X-first staging -------
// 256 thr = 4 waves; block = 64 och x 4 rows; single buffer; 2 blocks/CU.
__global__ __launch_bounds__(256, 2) void k_conv2g(
    const unsigned short* __restrict__ xbf, const unsigned short* __restrict__ wb,
    const float* __restrict__ g, const float* __restrict__ bias,
    float* __restrict__ out) {
    __shared__ unsigned short Wlds[9 * 64 * 32];   // 36864 B
    __shared__ unsigned short Xlds[6 * 66 * 32];   // 25344 B

    const int tid  = threadIdx.x;
    const int lane = tid & 63;
    const int wv   = tid >> 6;       // wave id 0..3 -> output row h0+wv
    const int l15  = lane & 15;
    const int hi   = lane >> 4;      // 0..3
    const int b  = blockIdx.z;
    const int ot = blockIdx.y;
    const int rt = blockIdx.x;
    const int h0 = rt * 4;

    const f32x4 zero4 = {0.f, 0.f, 0.f, 0.f};
    f32x4 acc[4][4];
    #pragma unroll
    for (int i = 0; i < 4; ++i)
        #pragma unroll
        for (int j = 0; j < 4; ++j) acc[i][j] = zero4;

    // zero X LDS once: pad cols (0,65) and out-of-image rows stay 0 for all chunks
    {
        unsigned int* p = (unsigned int*)Xlds;
        for (int i = tid; i < 6 * 66 * 32 / 2; i += 256) p[i] = 0u;
    }
    __syncthreads();

    const char* wsrc0 = (const char*)wb + (size_t)ot * 16 * 36864;
    const char* xsrc0 = (const char*)xbf + (size_t)b * 16 * 262144;   // 64*4096 per (b,cc)

    // per-lane fragment byte addresses (tap-invariant parts)
    int wfo[4], xco[4];
    #pragma unroll
    for (int mi = 0; mi < 4; ++mi) {
        const int o = mi * 16 + l15;
        wfo[mi] = ((o << 6) + (hi << 4)) ^ ((o & 6) << 3);
    }
    #pragma unroll
    for (int ni = 0; ni < 4; ++ni) xco[ni] = ni * 16 + l15;

    auto LOADW = [&](int tap, bf16x8* af) {
        #pragma unroll
        for (int mi = 0; mi < 4; ++mi)
            af[mi] = *(const bf16x8*)((const char*)Wlds + (tap << 12) + wfo[mi]);
    };
    auto LOADX = [&](int tap, bf16x8* bg) {
        const int ti = tap / 3, tj = tap - ti * 3;
        const int row = wv + ti;
        #pragma unroll
        for (int ni = 0; ni < 4; ++ni) {
            const int col = xco[ni] + tj;
            int byte = (((row * 66 + col) << 5) + (hi << 3)) << 1;
            byte ^= ((col & 6) << 3);
            bg[ni] = *(const bf16x8*)((const char*)Xlds + byte);
        }
    };

    for (int cc = 0; cc < NCHUNK; ++cc) {
        // ---- stage X FIRST (L3-resident, longest latency ages under the drain) ----
        const char* xsrc = xsrc0 + (size_t)cc * 262144;
        #pragma unroll
        for (int r = 0; r < 6; ++r) {
            const int h_in = h0 - 1 + r;
            if ((unsigned)h_in < 64u)
                gl_lds16(xsrc + (size_t)h_in * 4096 + tid * 16,
                         (char*)Xlds + r * 4224 + 64 + wv * 1024);
        }
        // ---- stage W: 9 x 4096B linear slabs (L2-resident) ----
        const char* wsrc = wsrc0 + (size_t)cc * 36864;
        #pragma unroll
        for (int r = 0; r < 9; ++r)
            gl_lds16(wsrc + r * 4096 + tid * 16,
                     (char*)Wlds + r * 4096 + wv * 1024);
        __syncthreads();

        // ---- compute: 9 taps, 2-tap-deep register pipeline ----
        bf16x8 af0[4], bg0[4], af1[4], bg1[4], af2[4], bg2[4];
        LOADW(0, af0); LOADX(0, bg0);
        LOADW(1, af1); LOADX(1, bg1);
        #pragma unroll
        for (int tap = 0; tap < 9; ++tap) {
            if (tap < 7) { LOADW(tap + 2, af2); LOADX(tap + 2, bg2); }
            __builtin_amdgcn_s_setprio(1);
            #pragma unroll
            for (int mi = 0; mi < 4; ++mi)
                #pragma unroll
                for (int ni = 0; ni < 4; ++ni)
                    acc[mi][ni] = __builtin_amdgcn_mfma_f32_16x16x32_bf16(
                        af0[mi], bg0[ni], acc[mi][ni], 0, 0, 0);
            __builtin_amdgcn_s_setprio(0);
            #pragma unroll
            for (int q = 0; q < 4; ++q) {
                af0[q] = af1[q]; bg0[q] = bg1[q];
                af1[q] = af2[q]; bg1[q] = bg2[q];
            }
        }
        if (cc != NCHUNK - 1) __syncthreads();
    }

    // ---- epilogue: *G, +bias, lrelu*gain, clamp, interior + batched borders ----
    {
        const int obase = ot * 64;
        const int orow = h0 + wv + 1;
        #pragma unroll
        for (int mi = 0; mi < 4; ++mi) {
            #pragma unroll
            for (int r = 0; r < 4; ++r) {
                const int o = obase + mi * 16 + hi * 4 + r;
                const float gg = g[b * COUT_ + o];
                const float bb = bias[o];
                float* op = out + ((size_t)(b * COUT_ + o) * 66 + orow) * 66;
                #pragma unroll
                for (int ni = 0; ni < 4; ++ni) {
                    float v = acc[mi][ni][r] * gg + bb;
                    v = (v >= 0.f ? v : v * 0.2f) * GAIN_;
                    v = fminf(fmaxf(v, -CLAMP_), CLAMP_);
                    op[ni * 16 + l15 + 1] = v;
                }
            }
        }
        // col borders for this block's 64 maps x 4 rows: 512 scalars
        #pragma unroll
        for (int k = 0; k < 2; ++k) {
            const int i = tid + k * 256;           // 0..511
            const int o = obase + (i >> 3);
            const int rr = (i >> 1) & 3;
            const int col = (i & 1) ? 65 : 0;
            out[((size_t)(b * COUT_ + o) * 66 + h0 + rr + 1) * 66 + col] = 0.f;
        }
        // top/bottom full border rows
        if (rt == 0 || rt == 15) {
            const int row = (rt == 0) ? 0 : 65;
            for (int i = tid; i < 64 * 66; i += 256) {
                const int o = obase + i / 66, col = i - (i / 66) * 66;
                out[((size_t)(b * COUT_ + o) * 66 + row) * 66 + col] = 0.f;
            }
        }
    }
}

// ---------------- launcher ----------------
extern "C" void kernel_launch(void* const* d_in, const int* in_sizes, int n_in,
                              void* d_out, int out_size, void* d_ws, size_t ws_size,
                              hipStream_t stream) {
    const float* x    = (const float*)d_in[0];
    const float* w    = (const float*)d_in[1];
    const float* aw   = (const float*)d_in[2];
    const float* ab   = (const float*)d_in[3];
    const float* cw   = (const float*)d_in[4];
    const float* bias = (const float*)d_in[5];
    const float* ema  = (const float*)d_in[6];
    float* out = (float*)d_out;

    float* wsf   = (float*)d_ws;
    float* s     = wsf;                 // 8192
    float* part  = wsf + 8192;          // 32
    float* alpha = wsf + 16512;         // 512
    float* Q     = wsf + 17024;         // 262144
    float* g     = wsf + 279168;        // 8192
    unsigned short* wb  = (unsigned short*)((char*)d_ws + 1179648);  // 4718592 B
    unsigned short* xbf = (unsigned short*)((char*)d_ws + 5898240);  // 67108864 B

    k_prepA <<<672, 256, 0, stream>>>(w, aw, ab, cw, s, part, alpha, Q, wb);
    k_prepB <<<2080, 256, 0, stream>>>(x, s, part, Q, alpha, ema, g, xbf);
    k_conv2g<<<dim3(16, 8, 16), 256, 0, stream>>>(xbf, wb, g, bias, out);
}

// Round 18
// 303.291 us; speedup vs baseline: 1.0070x; 1.0070x over previous
//
#include <hip/hip_runtime.h>

// ---------------- constants ----------------
#define B_     16
#define WDIM   512
#define CIN_   512
#define COUT_  512
#define HH     64
#define KC     32           // channels per K-chunk
#define NCHUNK (CIN_/KC)    // 16
#define AFFINE_WG 0.044194173824159216f   // 1/sqrt(512)
#define GAIN_  1.4142135623730951f
#define CLAMP_ 256.0f

typedef __attribute__((ext_vector_type(4))) float f32x4;
typedef __attribute__((ext_vector_type(8))) short bf16x8;
typedef __attribute__((ext_vector_type(8))) unsigned short u16x8;

__device__ __forceinline__ unsigned short f2bf(float f) {
    union { float f; unsigned u; } un; un.f = f;
    unsigned u = un.u;
    u += 0x7FFFu + ((u >> 16) & 1u);   // round-to-nearest-even
    return (unsigned short)(u >> 16);
}

__device__ __forceinline__ void gl_lds16(const void* g, void* l) {
    __builtin_amdgcn_global_load_lds(
        reinterpret_cast<const __attribute__((address_space(1))) unsigned int*>(
            reinterpret_cast<uintptr_t>(g)),
        reinterpret_cast<__attribute__((address_space(3))) unsigned int*>(
            reinterpret_cast<uintptr_t>(l)),
        16, 0, 0);
}

// ------- fused prep A: affine (32) | wnorm (512) | wprep (128) -------
__global__ void k_prepA(const float* __restrict__ w, const float* __restrict__ aw,
                        const float* __restrict__ ab, const float* __restrict__ cw,
                        float* __restrict__ s, float* __restrict__ part,
                        float* __restrict__ alpha, float* __restrict__ Q,
                        unsigned short* __restrict__ wb) {
    const int bi  = blockIdx.x;
    const int tid = threadIdx.x;
    __shared__ float redA[256];
    __shared__ float qsh[512];
    __shared__ float a_sh;
    __shared__ char tile[36864];

    if (bi < 32) {
        const int b = bi >> 1;
        const int c = ((bi & 1) << 8) + tid;
        const f32x4* wr = (const f32x4*)(w + (size_t)b * WDIM);
        const f32x4* ar = (const f32x4*)(aw + (size_t)c * WDIM);
        float acc = 0.f;
        #pragma unroll 4
        for (int k = 0; k < WDIM / 4; ++k) {
            f32x4 a = ar[k], bb = wr[k];
            acc += a[0]*bb[0] + a[1]*bb[1] + a[2]*bb[2] + a[3]*bb[3];
        }
        float sv = acc * AFFINE_WG + ab[c];
        s[b * CIN_ + c] = sv;
        redA[tid] = sv * sv;
        __syncthreads();
        for (int off = 128; off > 0; off >>= 1) {
            if (tid < off) redA[tid] += redA[tid + off];
            __syncthreads();
        }
        if (tid == 0) part[bi] = redA[0];
    } else if (bi < 544) {
        const int o = bi - 32;
        float tot = 0.f;
        #pragma unroll
        for (int half = 0; half < 2; ++half) {
            const int c = tid + half * 256;
            const float* p = cw + ((size_t)o * 512 + c) * 9;
            float qs = 0.f;
            #pragma unroll
            for (int t = 0; t < 9; ++t) { float v = p[t]; qs += v * v; }
            qsh[c] = qs; tot += qs;
        }
        redA[tid] = tot; __syncthreads();
        for (int off = 128; off > 0; off >>= 1) {
            if (tid < off) redA[tid] += redA[tid + off];
            __syncthreads();
        }
        if (tid == 0) { a_sh = rsqrtf(redA[0] * (1.0f / 4608.0f)); alpha[o] = a_sh; }
        __syncthreads();
        const float a2 = a_sh * a_sh;
        Q[(size_t)o * 512 + tid]       = a2 * qsh[tid];
        Q[(size_t)o * 512 + tid + 256] = a2 * qsh[tid + 256];
    } else {
        const int p = bi - 544;                   // 0..127 = ot*16+cc
        const int ot = p >> 4, cc = p & 15;
        const float* base = cw + ((size_t)(ot * 64) * 512 + cc * 32) * 9;
        #pragma unroll
        for (int k = 0; k < 18; ++k) {
            const int lin4 = tid + k * 256;       // f32x4 granule, 4608 total
            const int row  = lin4 / 72;           // o within tile
            const int i4   = lin4 - row * 72;
            const f32x4 v = *(const f32x4*)(base + (size_t)row * 4608 + i4 * 4);
            #pragma unroll
            for (int j = 0; j < 4; ++j) {
                const int e   = i4 * 4 + j;       // within row: c*9+tap
                const int c   = e / 9;
                const int tap = e - c * 9;
                const int byte = ((tap * 2048 + row * 32 + c) << 1) ^ ((row & 6) << 3);
                *(unsigned short*)(tile + byte) = f2bf(v[j]);
            }
        }
        __syncthreads();
        u16x8* dst = (u16x8*)(wb + (size_t)p * 18432);
        const u16x8* src = (const u16x8*)tile;
        #pragma unroll
        for (int k = 0; k < 9; ++k) dst[tid + k * 256] = src[tid + k * 256];
    }
}

// ---------------- fused prep B: g (32) | xprep (2048) ----------------
__global__ void k_prepB(const float* __restrict__ x, const float* __restrict__ s,
                        const float* __restrict__ part, const float* __restrict__ Q,
                        const float* __restrict__ alpha, const float* __restrict__ ema,
                        float* __restrict__ g, unsigned short* __restrict__ xbf) {
    const int bi  = blockIdx.x;
    const int tid = threadIdx.x;
    __shared__ float rs2_sh;
    __shared__ char tile[8 * 4096];

    if (bi < 32) {
        const int b = bi >> 1;
        const int o = ((bi & 1) << 8) + tid;
        if (tid == 0) {
            float t = 0.f;
            #pragma unroll
            for (int i = 0; i < 32; ++i) t += part[i];
            rs2_sh = 8192.0f / t;          // rs^2
        }
        __syncthreads();
        const f32x4* sh = (const f32x4*)(s + (size_t)b * CIN_);
        const f32x4* qq = (const f32x4*)(Q + (size_t)o * CIN_);
        float d = 0.f;
        #pragma unroll 4
        for (int k = 0; k < CIN_ / 4; ++k) {
            f32x4 a = sh[k], q4 = qq[k];
            d += a[0]*a[0]*q4[0] + a[1]*a[1]*q4[1] + a[2]*a[2]*q4[2] + a[3]*a[3]*q4[3];
        }
        const float ig = rsqrtf(ema[0]);
        g[b * COUT_ + o] = alpha[o] * rsqrtf(d * rs2_sh + 1e-8f) * ig;
    } else {
        if (tid == 0) {
            float t = 0.f;
            #pragma unroll
            for (int i = 0; i < 32; ++i) t += part[i];
            rs2_sh = rsqrtf(t * (1.0f / 8192.0f));   // rs
        }
        __syncthreads();
        const float rs = rs2_sh;
        const int blk = bi - 32;                   // 0..2047
        const int b  = blk >> 7;
        const int cc = (blk >> 3) & 15;
        const int rg = blk & 7;
        const int c   = tid >> 3;                  // 0..31
        const int k8  = tid & 7;                   // 8-col segment
        const float sc = s[b * CIN_ + cc * 32 + c] * rs;
        const float* src = x + (((size_t)(b * CIN_ + cc * 32 + c)) * HH + rg * 8) * HH + k8 * 8;
        #pragma unroll
        for (int row = 0; row < 8; ++row) {
            const f32x4 v0 = *(const f32x4*)(src + (size_t)row * HH);
            const f32x4 v1 = *(const f32x4*)(src + (size_t)row * HH + 4);
            #pragma unroll
            for (int q = 0; q < 8; ++q) {
                const float v = (q < 4) ? v0[q] : v1[q - 4];
                const int col = k8 * 8 + q + 1;                 // lds col 1..64
                const int byte = ((col * 64 + 2 * c) ^ ((col & 6) << 3)) - 64;
                *(unsigned short*)(tile + row * 4096 + byte) = f2bf(v * sc);
            }
        }
        __syncthreads();
        unsigned short* dst = xbf + ((size_t)(b * 16 + cc) * 64 + rg * 8) * 2048;
        const u16x8* tsrc = (const u16x8*)tile;
        #pragma unroll
        for (int k = 0; k < 8; ++k)
            *(u16x8*)(dst + (size_t)(tid + k * 256) * 8) = tsrc[tid + k * 256];
    }
}

// ------- main conv: R16 champion (one-tap-ahead pipeline) + batched borders -------
// 256 thr = 4 waves; block = 64 och x 4 rows; single buffer; 2 blocks/CU.
__global__ __launch_bounds__(256, 2) void k_conv2f(
    const unsigned short* __restrict__ xbf, const unsigned short* __restrict__ wb,
    const float* __restrict__ g, const float* __restrict__ bias,
    float* __restrict__ out) {
    __shared__ unsigned short Wlds[9 * 64 * 32];   // 36864 B
    __shared__ unsigned short Xlds[6 * 66 * 32];   // 25344 B

    const int tid  = threadIdx.x;
    const int lane = tid & 63;
    const int wv   = tid >> 6;       // wave id 0..3 -> output row h0+wv
    const int l15  = lane & 15;
    const int hi   = lane >> 4;      // 0..3
    const int b  = blockIdx.z;
    const int ot = blockIdx.y;
    const int rt = blockIdx.x;
    const int h0 = rt * 4;

    const f32x4 zero4 = {0.f, 0.f, 0.f, 0.f};
    f32x4 acc[4][4];
    #pragma unroll
    for (int i = 0; i < 4; ++i)
        #pragma unroll
        for (int j = 0; j < 4; ++j) acc[i][j] = zero4;

    // zero X LDS once: pad cols (0,65) and out-of-image rows stay 0 for all chunks
    {
        unsigned int* p = (unsigned int*)Xlds;
        for (int i = tid; i < 6 * 66 * 32 / 2; i += 256) p[i] = 0u;
    }
    __syncthreads();

    const char* wsrc0 = (const char*)wb + (size_t)ot * 16 * 36864;
    const char* xsrc0 = (const char*)xbf + (size_t)b * 16 * 262144;   // 64*4096 per (b,cc)

    // per-lane fragment byte addresses (tap-invariant parts)
    int wfo[4], xco[4];
    #pragma unroll
    for (int mi = 0; mi < 4; ++mi) {
        const int o = mi * 16 + l15;
        wfo[mi] = ((o << 6) + (hi << 4)) ^ ((o & 6) << 3);
    }
    #pragma unroll
    for (int ni = 0; ni < 4; ++ni) xco[ni] = ni * 16 + l15;

    for (int cc = 0; cc < NCHUNK; ++cc) {
        // ---- stage W: 9 x 4096B linear slabs (pre-swizzled in ws) ----
        const char* wsrc = wsrc0 + (size_t)cc * 36864;
        #pragma unroll
        for (int r = 0; r < 9; ++r)
            gl_lds16(wsrc + r * 4096 + tid * 16,
                     (char*)Wlds + r * 4096 + wv * 1024);
        // ---- stage X: up to 6 x 4096B row slabs into cols 1..64 (pre-swizzled) ----
        const char* xsrc = xsrc0 + (size_t)cc * 262144;
        #pragma unroll
        for (int r = 0; r < 6; ++r) {
            const int h_in = h0 - 1 + r;
            if ((unsigned)h_in < 64u)
                gl_lds16(xsrc + (size_t)h_in * 4096 + tid * 16,
                         (char*)Xlds + r * 4224 + 64 + wv * 1024);
        }
        __syncthreads();

        // ---- compute: 9 taps, software-pipelined one tap ahead ----
        bf16x8 afc[4], bgc[4], afn[4], bgn[4];
        {
            #pragma unroll
            for (int mi = 0; mi < 4; ++mi)
                afc[mi] = *(const bf16x8*)((const char*)Wlds + wfo[mi]);
            const int row0 = wv;
            #pragma unroll
            for (int ni = 0; ni < 4; ++ni) {
                const int col = xco[ni];
                int byte = (((row0 * 66 + col) << 5) + (hi << 3)) << 1;
                byte ^= ((col & 6) << 3);
                bgc[ni] = *(const bf16x8*)((const char*)Xlds + byte);
            }
        }
        #pragma unroll
        for (int tap = 0; tap < 9; ++tap) {
            if (tap < 8) {
                const int tn = tap + 1;
                const int tin = tn / 3, tjn = tn - tin * 3;
                #pragma unroll
                for (int mi = 0; mi < 4; ++mi)
                    afn[mi] = *(const bf16x8*)((const char*)Wlds + (tn << 12) + wfo[mi]);
                const int rown = wv + tin;
                #pragma unroll
                for (int ni = 0; ni < 4; ++ni) {
                    const int col = xco[ni] + tjn;
                    int byte = (((rown * 66 + col) << 5) + (hi << 3)) << 1;
                    byte ^= ((col & 6) << 3);
                    bgn[ni] = *(const bf16x8*)((const char*)Xlds + byte);
                }
            }
            __builtin_amdgcn_s_setprio(1);
            #pragma unroll
            for (int mi = 0; mi < 4; ++mi)
                #pragma unroll
                for (int ni = 0; ni < 4; ++ni)
                    acc[mi][ni] = __builtin_amdgcn_mfma_f32_16x16x32_bf16(
                        afc[mi], bgc[ni], acc[mi][ni], 0, 0, 0);
            __builtin_amdgcn_s_setprio(0);
            #pragma unroll
            for (int q = 0; q < 4; ++q) { afc[q] = afn[q]; bgc[q] = bgn[q]; }
        }
        if (cc != NCHUNK - 1) __syncthreads();
    }

    // ---- epilogue: *G, +bias, lrelu*gain, clamp, interior + batched borders ----
    {
        const int obase = ot * 64;
        const int orow = h0 + wv + 1;
        #pragma unroll
        for (int mi = 0; mi < 4; ++mi) {
            #pragma unroll
            for (int r = 0; r < 4; ++r) {
                const int o = obase + mi * 16 + hi * 4 + r;
                const float gg = g[b * COUT_ + o];
                const float bb = bias[o];
                float* op = out + ((size_t)(b * COUT_ + o) * 66 + orow) * 66;
                #pragma unroll
                for (int ni = 0; ni < 4; ++ni) {
                    float v = acc[mi][ni][r] * gg + bb;
                    v = (v >= 0.f ? v : v * 0.2f) * GAIN_;
                    v = fminf(fmaxf(v, -CLAMP_), CLAMP_);
                    op[ni * 16 + l15 + 1] = v;
                }
            }
        }
        // col borders for this block's 64 maps x 4 rows: 512 scalars
        #pragma unroll
        for (int k = 0; k < 2; ++k) {
            const int i = tid + k * 256;           // 0..511
            const int o = obase + (i >> 3);
            const int rr = (i >> 1) & 3;
            const int col = (i & 1) ? 65 : 0;
            out[((size_t)(b * COUT_ + o) * 66 + h0 + rr + 1) * 66 + col] = 0.f;
        }
        // top/bottom full border rows
        if (rt == 0 || rt == 15) {
            const int row = (rt == 0) ? 0 : 65;
            for (int i = tid; i < 64 * 66; i += 256) {
                const int o = obase + i / 66, col = i - (i / 66) * 66;
                out[((size_t)(b * COUT_ + o) * 66 + row) * 66 + col] = 0.f;
            }
        }
    }
}

// ---------------- launcher ----------------
extern "C" void kernel_launch(void* const* d_in, const int* in_sizes, int n_in,
                              void* d_out, int out_size, void* d_ws, size_t ws_size,
                              hipStream_t stream) {
    const float* x    = (const float*)d_in[0];
    const float* w    = (const float*)d_in[1];
    const float* aw   = (const float*)d_in[2];
    const float* ab   = (const float*)d_in[3];
    const float* cw   = (const float*)d_in[4];
    const float* bias = (const float*)d_in[5];
    const float* ema  = (const float*)d_in[6];
    float* out = (float*)d_out;

    float* wsf   = (float*)d_ws;
    float* s     = wsf;                 // 8192
    float* part  = wsf + 8192;          // 32
    float* alpha = wsf + 16512;         // 512
    float* Q     = wsf + 17024;         // 262144
    float* g     = wsf + 279168;        // 8192
    unsigned short* wb  = (unsigned short*)((char*)d_ws + 1179648);  // 4718592 B
    unsigned short* xbf = (unsigned short*)((char*)d_ws + 5898240);  // 67108864 B

    k_prepA <<<672, 256, 0, stream>>>(w, aw, ab, cw, s, part, alpha, Q, wb);
    k_prepB <<<2080, 256, 0, stream>>>(x, s, part, Q, alpha, ema, g, xbf);
    k_conv2f<<<dim3(16, 8, 16), 256, 0, stream>>>(xbf, wb, g, bias, out);
}